// Round 1
// baseline (169.857 us; speedup 1.0000x reference)
//
#include <hip/hip_runtime.h>

// YOLOv1 loss, fp32. S=7, B=2, C=20, D=30, IMG=448, CELL=64.
#define D_CH 30
#define N_CLS 20
#define CELL_SZ 64.0f
#define INV_CELL (1.0f / 64.0f)
#define INV_IMG (1.0f / 448.0f)
#define IMG_SZ 448.0f
#define L_COORD 5.0f
#define L_NOOBJ 0.5f

__device__ __forceinline__ float wave_reduce(float v) {
#pragma unroll
    for (int o = 32; o > 0; o >>= 1) v += __shfl_down(v, o, 64);
    return v;
}

__global__ __launch_bounds__(256) void yolo_loss_kernel(
    const float* __restrict__ fm, const float* __restrict__ bb,
    const int* __restrict__ lab, float* __restrict__ out,
    unsigned ncells, int ng, int G, int conf_blocks)
{
    float acc = 0.0f;
    const unsigned total = ncells * (unsigned)D_CH;

    if ((int)blockIdx.x < conf_blocks) {
        // ---- phase A: 0.5 * sum over all cells of conf^2 (channels 4 and 9) ----
        const unsigned total4 = total >> 2;
        const float4* fm4 = (const float4*)fm;
        unsigned tid = blockIdx.x * blockDim.x + threadIdx.x;
        unsigned stride = (unsigned)conf_blocks * blockDim.x;
        for (unsigned i = tid; i < total4; i += stride) {
            float4 v = fm4[i];
            unsigned ch0 = (i * 4u) % 30u;
            float e0 = v.x, e1 = v.y, e2 = v.z, e3 = v.w;
            unsigned c;
            c = ch0;                      if (c == 4u || c == 9u) acc += L_NOOBJ * e0 * e0;
            c = ch0 + 1u; if (c >= 30u) c -= 30u; if (c == 4u || c == 9u) acc += L_NOOBJ * e1 * e1;
            c = ch0 + 2u; if (c >= 30u) c -= 30u; if (c == 4u || c == 9u) acc += L_NOOBJ * e2 * e2;
            c = ch0 + 3u; if (c >= 30u) c -= 30u; if (c == 4u || c == 9u) acc += L_NOOBJ * e3 * e3;
        }
        // tail (only if total not divisible by 4)
        if (blockIdx.x == 0 && threadIdx.x == 0) {
            for (unsigned i = total4 << 2; i < total; ++i) {
                unsigned c = i % 30u;
                if (c == 4u || c == 9u) { float e = fm[i]; acc += L_NOOBJ * e * e; }
            }
        }
    } else {
        // ---- phase B: per-(n,g) terms ----
        int t = (blockIdx.x - conf_blocks) * blockDim.x + threadIdx.x;
        if (t < ng) {
            float4 box = ((const float4*)bb)[t];
            float x1 = box.x, y1 = box.y, x2 = box.z, y2 = box.w;
            float cx = 0.5f * (x1 + x2);
            float cy = 0.5f * (y1 + y2);
            float gw = x2 - x1, gh = y2 - y1;
            int col = (int)floorf(cx * INV_CELL); col = min(max(col, 0), 6);
            int row = (int)floorf(cy * INV_CELL); row = min(max(row, 0), 6);

            const float* cell = fm + ((size_t)(t / G) * 49 + (size_t)(row * 7 + col)) * D_CH;
            float c[D_CH];
            const float2* c2 = (const float2*)cell;
#pragma unroll
            for (int k = 0; k < 15; ++k) { float2 u = c2[k]; c[2 * k] = u.x; c[2 * k + 1] = u.y; }

            float tx = cx * INV_CELL - (float)col;
            float ty = cy * INV_CELL - (float)row;
            float stw = sqrtf(gw * INV_IMG);
            float sth = sqrtf(gh * INV_IMG);
            float a2 = fmaxf(x2 - x1, 0.0f) * fmaxf(y2 - y1, 0.0f);

            float ioub[2], pcb[2], coordb[2];
#pragma unroll
            for (int b = 0; b < 2; ++b) {
                float px = c[5 * b + 0], py = c[5 * b + 1];
                float pw = c[5 * b + 2], ph = c[5 * b + 3], pc = c[5 * b + 4];
                float pcx = (float)col * CELL_SZ + px * CELL_SZ;
                float pcy = (float)row * CELL_SZ + py * CELL_SZ;
                float pwa = pw * IMG_SZ, pha = ph * IMG_SZ;
                float bx1 = pcx - 0.5f * pwa, by1 = pcy - 0.5f * pha;
                float bx2 = pcx + 0.5f * pwa, by2 = pcy + 0.5f * pha;
                float ix1 = fmaxf(bx1, x1), iy1 = fmaxf(by1, y1);
                float ix2 = fminf(bx2, x2), iy2 = fminf(by2, y2);
                float inter = fmaxf(ix2 - ix1, 0.0f) * fmaxf(iy2 - iy1, 0.0f);
                float a1 = fmaxf(bx2 - bx1, 0.0f) * fmaxf(by2 - by1, 0.0f);
                ioub[b] = inter / (a1 + a2 - inter + 1e-6f);
                pcb[b] = pc;
                float dx = px - tx, dy = py - ty;
                float dw = sqrtf(fmaxf(pw, 0.0f)) - stw;
                float dh = sqrtf(fmaxf(ph, 0.0f)) - sth;
                coordb[b] = dx * dx + dy * dy + dw * dw + dh * dh;
            }
            // jnp.argmax tie-break: first max index -> pick 1 only if strictly greater
            int sel = (ioub[1] > ioub[0]) ? 1 : 0;
            acc += L_COORD * coordb[sel];
            float dpc = pcb[sel] - ioub[sel];
            acc += dpc * dpc;
            acc -= L_NOOBJ * pcb[sel] * pcb[sel];

            int lbl = lab[t];
#pragma unroll
            for (int k = 0; k < N_CLS; ++k) {
                float d = c[10 + k] - (k == lbl ? 1.0f : 0.0f);
                acc += d * d;
            }
        }
    }

    // ---- block reduce (256 threads = 4 waves) + one atomic per block ----
    __shared__ float sm[4];
    float wv = wave_reduce(acc);
    int lane = threadIdx.x & 63;
    int wid = threadIdx.x >> 6;
    if (lane == 0) sm[wid] = wv;
    __syncthreads();
    if (threadIdx.x == 0) {
        float s = sm[0] + sm[1] + sm[2] + sm[3];
        atomicAdd(out, s);
    }
}

extern "C" void kernel_launch(void* const* d_in, const int* in_sizes, int n_in,
                              void* d_out, int out_size, void* d_ws, size_t ws_size,
                              hipStream_t stream) {
    const float* fm = (const float*)d_in[0];
    const float* bb = (const float*)d_in[1];
    const int* lab = (const int*)d_in[2];
    float* out = (float*)d_out;

    int fm_elems = in_sizes[0];
    int ng = in_sizes[2];                 // N * G
    int n = fm_elems / (49 * D_CH);       // N
    int G = ng / n;                       // boxes per image
    unsigned ncells = (unsigned)n * 49u;

    hipMemsetAsync(out, 0, sizeof(float), stream);

    const int conf_blocks = 2048;                 // grid-stride full-featmap read
    const int ng_blocks = (ng + 255) / 256;       // one thread per (n,g)
    yolo_loss_kernel<<<conf_blocks + ng_blocks, 256, 0, stream>>>(
        fm, bb, lab, out, ncells, ng, G, conf_blocks);
}

// Round 2
// 161.133 us; speedup vs baseline: 1.0541x; 1.0541x over previous
//
#include <hip/hip_runtime.h>

// YOLOv1 loss, fp32. S=7, B=2, C=20, D=30, IMG=448, CELL=64.
#define D_CH 30
#define CELL_SZ 64.0f
#define INV_CELL (1.0f / 64.0f)
#define INV_IMG (1.0f / 448.0f)
#define IMG_SZ 448.0f
#define L_COORD 5.0f
#define L_NOOBJ 0.5f

#define CONF_BLOCKS 2048
#define BLK 256
// stride between a thread's consecutive float4s in phase A
#define STRIDE4 ((unsigned)CONF_BLOCKS * (unsigned)BLK)
// channel advance constants (compile-time): channel of float4 i is (4*i)%30
#define DCH1 ((unsigned)(((unsigned long long)STRIDE4 * 4ull) % 30ull))   // per +STRIDE4
#define DCH4 ((unsigned)(((unsigned long long)STRIDE4 * 16ull) % 30ull))  // per +4*STRIDE4

__device__ __forceinline__ float wave_reduce(float v) {
#pragma unroll
    for (int o = 32; o > 0; o >>= 1) v += __shfl_down(v, o, 64);
    return v;
}

// Base channel ch (even, 0..28). float4 holds channels ch..ch+3.
// conf channels are 4 (even -> elem 0 or 2) and 9 (odd -> elem 1 or 3):
//   ch==4 -> .x, ch==2 -> .z, ch==8 -> .y, ch==6 -> .w ; else no conf present.
__device__ __forceinline__ float pick_conf_sq(float4 v, unsigned ch) {
    float p = 0.0f;
    p = (ch == 2u) ? v.z : p;
    p = (ch == 4u) ? v.x : p;
    p = (ch == 6u) ? v.w : p;
    p = (ch == 8u) ? v.y : p;
    return p * p;
}

__global__ __launch_bounds__(BLK) void yolo_loss_kernel(
    const float* __restrict__ fm, const float* __restrict__ bb,
    const int* __restrict__ lab, float* __restrict__ out,
    unsigned total /*ncells*30*/, int ng, int G)
{
    float acc = 0.0f;

    if (blockIdx.x < CONF_BLOCKS) {
        // ---- phase A: sum of conf^2 over whole featmap (channels 4, 9) ----
        const float4* __restrict__ fm4 = (const float4*)fm;
        const unsigned total4 = total >> 2;
        unsigned i = blockIdx.x * BLK + threadIdx.x;
        unsigned ch = (4u * i) % 30u;   // one-time magic modulo
        float cacc = 0.0f;

        while (i + 3u * STRIDE4 < total4) {
            float4 v0 = fm4[i];
            float4 v1 = fm4[i + STRIDE4];
            float4 v2 = fm4[i + 2u * STRIDE4];
            float4 v3 = fm4[i + 3u * STRIDE4];
            unsigned c1 = ch + DCH1; if (c1 >= 30u) c1 -= 30u;
            unsigned c2 = c1 + DCH1; if (c2 >= 30u) c2 -= 30u;
            unsigned c3 = c2 + DCH1; if (c3 >= 30u) c3 -= 30u;
            cacc += pick_conf_sq(v0, ch);
            cacc += pick_conf_sq(v1, c1);
            cacc += pick_conf_sq(v2, c2);
            cacc += pick_conf_sq(v3, c3);
            ch += DCH4; if (ch >= 30u) ch -= 30u;
            i += 4u * STRIDE4;
        }
        // strided leftovers (<4 per thread)
        for (; i < total4; i += STRIDE4) {
            float4 v = fm4[i];
            cacc += pick_conf_sq(v, (4u * i) % 30u);
        }
        // scalar tail if total % 4 != 0 (not hit for N=16384, kept for generality)
        if (blockIdx.x == 0 && threadIdx.x == 0) {
            for (unsigned f = total4 << 2; f < total; ++f) {
                unsigned c = f % 30u;
                if (c == 4u || c == 9u) { float e = fm[f]; cacc += e * e; }
            }
        }
        acc = L_NOOBJ * cacc;
    } else {
        // ---- phase B: per-(n,g) terms ----
        int t = (blockIdx.x - CONF_BLOCKS) * BLK + threadIdx.x;
        if (t < ng) {
            float4 box = ((const float4*)bb)[t];
            float x1 = box.x, y1 = box.y, x2 = box.z, y2 = box.w;
            float cx = 0.5f * (x1 + x2);
            float cy = 0.5f * (y1 + y2);
            float gw = x2 - x1, gh = y2 - y1;
            int col = (int)floorf(cx * INV_CELL); col = min(max(col, 0), 6);
            int row = (int)floorf(cy * INV_CELL); row = min(max(row, 0), 6);

            const float* __restrict__ cell =
                fm + ((size_t)(t / G) * 49 + (size_t)(row * 7 + col)) * D_CH;
            const float2* __restrict__ c2 = (const float2*)cell;  // 120B cells -> 8B aligned
            float2 u0 = c2[0];  // x0 y0
            float2 u1 = c2[1];  // w0 h0
            float2 u2 = c2[2];  // c0 x1
            float2 u3 = c2[3];  // y1 w1
            float2 u4 = c2[4];  // h1 c1

            float tx = cx * INV_CELL - (float)col;
            float ty = cy * INV_CELL - (float)row;
            float stw = sqrtf(gw * INV_IMG);
            float sth = sqrtf(gh * INV_IMG);
            float ga = fmaxf(gw, 0.0f) * fmaxf(gh, 0.0f);

            float px[2] = {u0.x, u2.y};
            float py[2] = {u0.y, u3.x};
            float pw[2] = {u1.x, u3.y};
            float ph[2] = {u1.y, u4.x};
            float pc[2] = {u2.x, u4.y};

            float ioub[2], coordb[2];
#pragma unroll
            for (int b = 0; b < 2; ++b) {
                float pcx = ((float)col + px[b]) * CELL_SZ;
                float pcy = ((float)row + py[b]) * CELL_SZ;
                float pwa = pw[b] * IMG_SZ, pha = ph[b] * IMG_SZ;
                float bx1 = pcx - 0.5f * pwa, by1 = pcy - 0.5f * pha;
                float bx2 = pcx + 0.5f * pwa, by2 = pcy + 0.5f * pha;
                float ix1 = fmaxf(bx1, x1), iy1 = fmaxf(by1, y1);
                float ix2 = fminf(bx2, x2), iy2 = fminf(by2, y2);
                float inter = fmaxf(ix2 - ix1, 0.0f) * fmaxf(iy2 - iy1, 0.0f);
                float a1 = fmaxf(bx2 - bx1, 0.0f) * fmaxf(by2 - by1, 0.0f);
                ioub[b] = inter / (a1 + ga - inter + 1e-6f);
                float dx = px[b] - tx, dy = py[b] - ty;
                float dw = sqrtf(fmaxf(pw[b], 0.0f)) - stw;
                float dh = sqrtf(fmaxf(ph[b], 0.0f)) - sth;
                coordb[b] = dx * dx + dy * dy + dw * dw + dh * dh;
            }
            // jnp.argmax tie-break: first max -> pick box1 only if strictly greater
            int sel = (ioub[1] > ioub[0]) ? 1 : 0;
            acc += L_COORD * coordb[sel];
            float dpc = pc[sel] - ioub[sel];
            acc += dpc * dpc;
            acc -= L_NOOBJ * pc[sel] * pc[sel];

            // class term: sum (c - onehot)^2 = sum c^2 - 2*c[lbl] + 1
            float sq = 0.0f;
#pragma unroll
            for (int k = 0; k < 10; ++k) {
                float2 u = c2[5 + k];
                sq = fmaf(u.x, u.x, fmaf(u.y, u.y, sq));
            }
            float cl = cell[10 + lab[t]];
            acc += sq - 2.0f * cl + 1.0f;
        }
    }

    // ---- block reduce (256 threads = 4 waves) + one atomic per block ----
    __shared__ float sm[4];
    float wv = wave_reduce(acc);
    int lane = threadIdx.x & 63;
    int wid = threadIdx.x >> 6;
    if (lane == 0) sm[wid] = wv;
    __syncthreads();
    if (threadIdx.x == 0) {
        float s = sm[0] + sm[1] + sm[2] + sm[3];
        atomicAdd(out, s);
    }
}

extern "C" void kernel_launch(void* const* d_in, const int* in_sizes, int n_in,
                              void* d_out, int out_size, void* d_ws, size_t ws_size,
                              hipStream_t stream) {
    const float* fm = (const float*)d_in[0];
    const float* bb = (const float*)d_in[1];
    const int* lab = (const int*)d_in[2];
    float* out = (float*)d_out;

    int fm_elems = in_sizes[0];
    int ng = in_sizes[2];                 // N * G
    int n = fm_elems / (49 * D_CH);       // N
    int G = ng / n;                       // boxes per image
    unsigned total = (unsigned)n * 49u * (unsigned)D_CH;

    hipMemsetAsync(out, 0, sizeof(float), stream);

    const int ng_blocks = (ng + BLK - 1) / BLK;   // one thread per (n,g)
    yolo_loss_kernel<<<CONF_BLOCKS + ng_blocks, BLK, 0, stream>>>(
        fm, bb, lab, out, total, ng, G);
}

// Round 3
// 146.875 us; speedup vs baseline: 1.1565x; 1.0971x over previous
//
#include <hip/hip_runtime.h>

// YOLOv1 loss, fp32. S=7, B=2, C=20, D=30, IMG=448, CELL=64.
#define D_CH 30
#define CELL_SZ 64.0f
#define INV_CELL (1.0f / 64.0f)
#define INV_IMG (1.0f / 448.0f)
#define IMG_SZ 448.0f
#define L_COORD 5.0f
#define L_NOOBJ 0.5f

#define CONF_BLOCKS 2048
#define BLK 256
// stride between a thread's consecutive float4s in phase A
#define STRIDE4 ((unsigned)CONF_BLOCKS * (unsigned)BLK)
// channel advance constants (compile-time): channel of float4 i is (4*i)%30
#define DCH1 ((unsigned)(((unsigned long long)STRIDE4 * 4ull) % 30ull))   // = 2
#define DCH4 ((unsigned)(((unsigned long long)STRIDE4 * 16ull) % 30ull))  // = 8

__device__ __forceinline__ float wave_reduce(float v) {
#pragma unroll
    for (int o = 32; o > 0; o >>= 1) v += __shfl_down(v, o, 64);
    return v;
}

// Base channel ch (even, 0..28). float4 holds channels ch..ch+3.
// conf channels are 4 and 9: ch==4 -> .x, ch==2 -> .z, ch==8 -> .y, ch==6 -> .w.
__device__ __forceinline__ float pick_conf_sq(float4 v, unsigned ch) {
    float p = 0.0f;
    p = (ch == 2u) ? v.z : p;
    p = (ch == 4u) ? v.x : p;
    p = (ch == 6u) ? v.w : p;
    p = (ch == 8u) ? v.y : p;
    return p * p;
}

__global__ __launch_bounds__(BLK) void yolo_partial_kernel(
    const float* __restrict__ fm, const float* __restrict__ bb,
    const int* __restrict__ lab, float* __restrict__ partials,
    unsigned total /*ncells*30*/, int ng, int G)
{
    float acc = 0.0f;

    if (blockIdx.x < CONF_BLOCKS) {
        // ---- phase A: sum of conf^2 over whole featmap (channels 4, 9) ----
        const float4* __restrict__ fm4 = (const float4*)fm;
        const unsigned total4 = total >> 2;
        unsigned i = blockIdx.x * BLK + threadIdx.x;
        unsigned ch = (4u * i) % 30u;   // one-time magic modulo
        float cacc = 0.0f;

        while (i + 3u * STRIDE4 < total4) {
            float4 v0 = fm4[i];
            float4 v1 = fm4[i + STRIDE4];
            float4 v2 = fm4[i + 2u * STRIDE4];
            float4 v3 = fm4[i + 3u * STRIDE4];
            unsigned c1 = ch + DCH1; if (c1 >= 30u) c1 -= 30u;
            unsigned c2 = c1 + DCH1; if (c2 >= 30u) c2 -= 30u;
            unsigned c3 = c2 + DCH1; if (c3 >= 30u) c3 -= 30u;
            cacc += pick_conf_sq(v0, ch);
            cacc += pick_conf_sq(v1, c1);
            cacc += pick_conf_sq(v2, c2);
            cacc += pick_conf_sq(v3, c3);
            ch += DCH4; if (ch >= 30u) ch -= 30u;
            i += 4u * STRIDE4;
        }
        // strided leftovers (<4 per thread)
        for (; i < total4; i += STRIDE4) {
            float4 v = fm4[i];
            cacc += pick_conf_sq(v, (4u * i) % 30u);
        }
        // scalar tail if total % 4 != 0 (not hit for N=16384)
        if (blockIdx.x == 0 && threadIdx.x == 0) {
            for (unsigned f = total4 << 2; f < total; ++f) {
                unsigned c = f % 30u;
                if (c == 4u || c == 9u) { float e = fm[f]; cacc += e * e; }
            }
        }
        acc = L_NOOBJ * cacc;
    } else {
        // ---- phase B: per-(n,g) terms ----
        int t = (blockIdx.x - CONF_BLOCKS) * BLK + threadIdx.x;
        if (t < ng) {
            float4 box = ((const float4*)bb)[t];
            float x1 = box.x, y1 = box.y, x2 = box.z, y2 = box.w;
            float cx = 0.5f * (x1 + x2);
            float cy = 0.5f * (y1 + y2);
            float gw = x2 - x1, gh = y2 - y1;
            int col = (int)floorf(cx * INV_CELL); col = min(max(col, 0), 6);
            int row = (int)floorf(cy * INV_CELL); row = min(max(row, 0), 6);

            const float* __restrict__ cell =
                fm + ((size_t)(t / G) * 49 + (size_t)(row * 7 + col)) * D_CH;
            const float2* __restrict__ c2 = (const float2*)cell;  // 120B cells -> 8B aligned
            float2 u0 = c2[0];  // x0 y0
            float2 u1 = c2[1];  // w0 h0
            float2 u2 = c2[2];  // c0 x1
            float2 u3 = c2[3];  // y1 w1
            float2 u4 = c2[4];  // h1 c1

            float tx = cx * INV_CELL - (float)col;
            float ty = cy * INV_CELL - (float)row;
            float stw = sqrtf(gw * INV_IMG);
            float sth = sqrtf(gh * INV_IMG);
            float ga = fmaxf(gw, 0.0f) * fmaxf(gh, 0.0f);

            float px[2] = {u0.x, u2.y};
            float py[2] = {u0.y, u3.x};
            float pw[2] = {u1.x, u3.y};
            float ph[2] = {u1.y, u4.x};
            float pc[2] = {u2.x, u4.y};

            float ioub[2], coordb[2];
#pragma unroll
            for (int b = 0; b < 2; ++b) {
                float pcx = ((float)col + px[b]) * CELL_SZ;
                float pcy = ((float)row + py[b]) * CELL_SZ;
                float pwa = pw[b] * IMG_SZ, pha = ph[b] * IMG_SZ;
                float bx1 = pcx - 0.5f * pwa, by1 = pcy - 0.5f * pha;
                float bx2 = pcx + 0.5f * pwa, by2 = pcy + 0.5f * pha;
                float ix1 = fmaxf(bx1, x1), iy1 = fmaxf(by1, y1);
                float ix2 = fminf(bx2, x2), iy2 = fminf(by2, y2);
                float inter = fmaxf(ix2 - ix1, 0.0f) * fmaxf(iy2 - iy1, 0.0f);
                float a1 = fmaxf(bx2 - bx1, 0.0f) * fmaxf(by2 - by1, 0.0f);
                ioub[b] = inter / (a1 + ga - inter + 1e-6f);
                float dx = px[b] - tx, dy = py[b] - ty;
                float dw = sqrtf(fmaxf(pw[b], 0.0f)) - stw;
                float dh = sqrtf(fmaxf(ph[b], 0.0f)) - sth;
                coordb[b] = dx * dx + dy * dy + dw * dw + dh * dh;
            }
            // jnp.argmax tie-break: first max -> pick box1 only if strictly greater
            int sel = (ioub[1] > ioub[0]) ? 1 : 0;
            acc += L_COORD * coordb[sel];
            float dpc = pc[sel] - ioub[sel];
            acc += dpc * dpc;
            acc -= L_NOOBJ * pc[sel] * pc[sel];

            // class term: sum (c - onehot)^2 = sum c^2 - 2*c[lbl] + 1
            float sq = 0.0f;
#pragma unroll
            for (int k = 0; k < 10; ++k) {
                float2 u = c2[5 + k];
                sq = fmaf(u.x, u.x, fmaf(u.y, u.y, sq));
            }
            float cl = cell[10 + lab[t]];
            acc += sq - 2.0f * cl + 1.0f;
        }
    }

    // ---- block reduce (256 threads = 4 waves) -> one partial per block ----
    __shared__ float sm[4];
    float wv = wave_reduce(acc);
    int lane = threadIdx.x & 63;
    int wid = threadIdx.x >> 6;
    if (lane == 0) sm[wid] = wv;
    __syncthreads();
    if (threadIdx.x == 0) {
        partials[blockIdx.x] = sm[0] + sm[1] + sm[2] + sm[3];
    }
}

__global__ __launch_bounds__(BLK) void yolo_reduce_kernel(
    const float* __restrict__ partials, float* __restrict__ out, int n)
{
    float a = 0.0f;
    for (int i = threadIdx.x; i < n; i += BLK) a += partials[i];
    __shared__ float sm[4];
    float wv = wave_reduce(a);
    int lane = threadIdx.x & 63;
    int wid = threadIdx.x >> 6;
    if (lane == 0) sm[wid] = wv;
    __syncthreads();
    if (threadIdx.x == 0) out[0] = sm[0] + sm[1] + sm[2] + sm[3];
}

extern "C" void kernel_launch(void* const* d_in, const int* in_sizes, int n_in,
                              void* d_out, int out_size, void* d_ws, size_t ws_size,
                              hipStream_t stream) {
    const float* fm = (const float*)d_in[0];
    const float* bb = (const float*)d_in[1];
    const int* lab = (const int*)d_in[2];
    float* out = (float*)d_out;
    float* partials = (float*)d_ws;

    int fm_elems = in_sizes[0];
    int ng = in_sizes[2];                 // N * G
    int n = fm_elems / (49 * D_CH);       // N
    int G = ng / n;                       // boxes per image
    unsigned total = (unsigned)n * 49u * (unsigned)D_CH;

    const int ng_blocks = (ng + BLK - 1) / BLK;   // one thread per (n,g)
    const int nblocks = CONF_BLOCKS + ng_blocks;

    yolo_partial_kernel<<<nblocks, BLK, 0, stream>>>(
        fm, bb, lab, partials, total, ng, G);
    yolo_reduce_kernel<<<1, BLK, 0, stream>>>(partials, out, nblocks);
}